// Round 3
// baseline (742.910 us; speedup 1.0000x reference)
//
#include <hip/hip_runtime.h>
#include <hip/hip_bf16.h>
#include <math.h>

#define GK 2048
#define NCB 16   // query-side partial stride

typedef __attribute__((ext_vector_type(8))) short bf16x8;
typedef __attribute__((ext_vector_type(4))) float f32x4;
typedef __attribute__((ext_vector_type(4))) float f4v;
typedef __attribute__((ext_vector_type(4))) unsigned short u16x4;
typedef __attribute__((ext_vector_type(8))) unsigned short u16x8;

__device__ __forceinline__ unsigned short f2bf(float x) {
    unsigned int u = __float_as_uint(x);
    u += 0x7fffu + ((u >> 16) & 1u);
    return (unsigned short)(u >> 16);
}

__device__ __forceinline__ void gl_lds16(const void* g, void* l) {
    __builtin_amdgcn_global_load_lds(
        (const __attribute__((address_space(1))) unsigned int*)g,
        (__attribute__((address_space(3))) unsigned int*)l, 16, 0, 0);
}

// ---------- conversion kernels ----------
__global__ void cvt_flat_kernel(const float* __restrict__ src,
                                unsigned short* __restrict__ dst, long n) {
    long i = ((long)blockIdx.x * 256 + threadIdx.x) * 8;
    if (i >= n) return;
    f4v a = *(const f4v*)(src + i);
    f4v b = *(const f4v*)(src + i + 4);
    u16x4 r0, r1;
    r0[0] = f2bf(a[0]); r0[1] = f2bf(a[1]); r0[2] = f2bf(a[2]); r0[3] = f2bf(a[3]);
    r1[0] = f2bf(b[0]); r1[1] = f2bf(b[1]); r1[2] = f2bf(b[2]); r1[3] = f2bf(b[3]);
    *(u16x4*)(dst + i) = r0;
    *(u16x4*)(dst + i + 4) = r1;
}

__global__ void cvt_w_kernel(const float* __restrict__ src, long ldw,
                             unsigned short* __restrict__ dst) {
    int o = blockIdx.x;
    int tid = threadIdx.x;
    const float* s = src + (size_t)o * ldw;
    unsigned short* d = dst + (size_t)o * 2048;
#pragma unroll
    for (int k = 0; k < 8; k++) {
        int c = tid + (k << 8);
        d[c] = f2bf(s[c]);
    }
}

__global__ void extract_w3_kernel(const float* __restrict__ Wq,
                                  const float* __restrict__ Wt,
                                  float* __restrict__ w3q, float* __restrict__ w3t) {
    int o = blockIdx.x * 256 + threadIdx.x;
    w3q[o] = Wq[(size_t)o * 3073 + 3072];
    w3t[o] = Wt[(size_t)o * 5121 + 3072];
}

// ---------- per-batch constant D[b][o] ----------
template <int KLEN>
__global__ __launch_bounds__(256) void dconst_kernel(
    const float* __restrict__ W, long ldw,
    const float* __restrict__ bias,
    const float* __restrict__ query,
    const float* __restrict__ qctx,
    float* __restrict__ Dout) {
    int tid = threadIdx.x;
    int wave = tid >> 6, lane = tid & 63;
    int o = blockIdx.x * 4 + wave;
    const float* wrow = W + (size_t)o * ldw + 2048;
    float acc[16];
#pragma unroll
    for (int b2 = 0; b2 < 16; b2++) acc[b2] = 0.f;
    for (int i = lane; i < KLEN; i += 64) {
        if (KLEN == 1024 || i < 1024) {
            float wv = wrow[i];
            const float* qp = query + i;
#pragma unroll
            for (int b2 = 0; b2 < 16; b2++) acc[b2] += wv * qp[b2 * 1024];
        } else {
            float wv = wrow[i + 1];  // skip alphas column at 3072
            const float* cp = qctx + (i - 1024);
#pragma unroll
            for (int b2 = 0; b2 < 16; b2++) acc[b2] += wv * cp[b2 * 2048];
        }
    }
#pragma unroll
    for (int b2 = 0; b2 < 16; b2++) {
        float v = acc[b2];
        for (int off = 1; off < 64; off <<= 1) v += __shfl_xor(v, off);
        if (lane == 0) Dout[(b2 << 11) + o] = v + bias[o];
    }
}

// ---------- query-side fused GEMM (128x128 tile, m97 structure) ----------
template <int LOG_RPB>
__global__ __launch_bounds__(256) void gemm_score(
    const unsigned short* __restrict__ A,
    const unsigned short* __restrict__ Bt,
    const float* __restrict__ Dc,
    const float* __restrict__ avec,
    const float* __restrict__ w3,
    const float* __restrict__ tvec,
    float* __restrict__ partial,
    int row0) {
    __shared__ unsigned short As[128 * 32];
    __shared__ unsigned short Bs[128 * 32];
    __shared__ float red[128][2];

    int nwg = gridDim.x;
    int bid = blockIdx.x;
    int q8 = nwg >> 3;
    int wg = (bid & 7) * q8 + (bid >> 3);
    int rb = wg >> 4, cb = wg & 15;

    int tid = threadIdx.x;
    int wave = tid >> 6, lane = tid & 63;
    int wr = wave >> 1, wc = wave & 1;
    int l15 = lane & 15, lhi = lane >> 4;

    const unsigned short* Ab = A + (size_t)rb * 128 * GK;
    const unsigned short* Bb = Bt + (size_t)cb * 128 * GK;

    int r0 = tid >> 2, c0 = (tid & 3) << 3;

    f32x4 acc[4][4];
#pragma unroll
    for (int i = 0; i < 4; i++)
#pragma unroll
        for (int j = 0; j < 4; j++) acc[i][j] = (f32x4)0.f;

    unsigned short* AsW0 = As + (wave << 9);
    unsigned short* AsW1 = As + 2048 + (wave << 9);
    unsigned short* BsW0 = Bs + (wave << 9);
    unsigned short* BsW1 = Bs + 2048 + (wave << 9);

    for (int k0 = 0; k0 < GK; k0 += 32) {
        __syncthreads();
        gl_lds16(Ab + (size_t)r0 * GK + k0 + c0, AsW0);
        gl_lds16(Ab + (size_t)(r0 + 64) * GK + k0 + c0, AsW1);
        gl_lds16(Bb + (size_t)r0 * GK + k0 + c0, BsW0);
        gl_lds16(Bb + (size_t)(r0 + 64) * GK + k0 + c0, BsW1);
        __syncthreads();
        bf16x8 a[4], b[4];
#pragma unroll
        for (int mi = 0; mi < 4; mi++)
            a[mi] = *(const bf16x8*)(As + (((wr << 6) + (mi << 4) + l15) << 5) + (lhi << 3));
#pragma unroll
        for (int ni = 0; ni < 4; ni++)
            b[ni] = *(const bf16x8*)(Bs + (((wc << 6) + (ni << 4) + l15) << 5) + (lhi << 3));
#pragma unroll
        for (int mi = 0; mi < 4; mi++)
#pragma unroll
            for (int ni = 0; ni < 4; ni++)
                acc[mi][ni] = __builtin_amdgcn_mfma_f32_16x16x32_bf16(a[mi], b[ni], acc[mi][ni], 0, 0, 0);
    }

    int grow_base = row0 + (rb << 7) + (wr << 6);
    int bb = grow_base >> LOG_RPB;
    int gcol = (cb << 7) + (wc << 6) + l15;
    float Dco[4], w3o[4], tv[4];
#pragma unroll
    for (int ni = 0; ni < 4; ni++) {
        int o = gcol + (ni << 4);
        Dco[ni] = Dc[(bb << 11) + o];
        w3o[ni] = w3[o];
        tv[ni] = tvec[o];
    }
#pragma unroll
    for (int mi = 0; mi < 4; mi++) {
#pragma unroll
        for (int j = 0; j < 4; j++) {
            int rloc = (mi << 4) + (lhi << 2) + j;
            float av = avec[grow_base + rloc];
            float s = 0.f;
#pragma unroll
            for (int ni = 0; ni < 4; ni++) {
                float x = acc[mi][ni][j] + Dco[ni] + av * w3o[ni];
                x = fminf(fmaxf(x, -15.f), 15.f);
                float e = __expf(2.f * x);
                s += ((e - 1.f) / (e + 1.f)) * tv[ni];
            }
#pragma unroll
            for (int off = 1; off < 16; off <<= 1) s += __shfl_xor(s, off);
            if (l15 == 0) red[(wr << 6) + rloc][wc] = s;
        }
    }
    __syncthreads();
    if (tid < 128) {
        partial[(size_t)(row0 + (rb << 7) + tid) * NCB + cb] = red[tid][0] + red[tid][1];
    }
}

// ---------- text-side 256x256 8-phase GEMM, A = f32 reg-staged (fused cvt) ----------
// LDS layout (ushort units): XA=0, XB=16384, YA=32768, YB=49152, red @65536 (float[256][4])
// Swizzle: LDS chunk position p of row r holds global 16B-chunk p ^ (r&7); read applies same XOR.
#define MFMA16(A, B, C) __builtin_amdgcn_mfma_f32_16x16x32_bf16(A, B, C, 0, 0, 0)

#define LDA8(dst, ABASE, MI, KK) { \
    int _r = (wr << 7) + ((MI) << 4) + l15; \
    dst = *(const bf16x8*)(lds + (ABASE) + (_r << 6) + (((((KK) << 2) | lhi) ^ (_r & 7)) << 3)); }

#define LDB8(dst, BBASE, NI, KK) { \
    int _r = (wc << 6) + ((NI) << 4) + l15; \
    dst = *(const bf16x8*)(lds + (BBASE) + (_r << 6) + (((((KK) << 2) | lhi) ^ (_r & 7)) << 3)); }

// B staging: global_load_lds, pre-swizzled global source, linear LDS dest (128 rows x 64 cols)
#define STB(GR0, K0, LB) do { \
    gl_lds16(Bt + (size_t)((GR0) + (wid << 3) + rr) * GK + (K0) + ((cch ^ rr) << 3), lds + (LB) + (wid << 9)); \
    gl_lds16(Bt + (size_t)((GR0) + 64 + (wid << 3) + rr) * GK + (K0) + ((cch ^ rr) << 3), lds + (LB) + 4096 + (wid << 9)); \
  } while (0)

// A staging, phase-split: ALOAD issues 4 f32 dwordx4 (128 rows x 64 cols slice);
// AWRITE (>=2 phases later) converts to bf16 and ds_writes (contiguous 1024B/wave pattern).
#define ALOAD(R, GR0, K0) do { \
    const float* _p = A32 + (size_t)((GR0) + (wid << 3) + rr) * GK + (K0) + gq; \
    R##0 = *(const f4v*)_p; \
    R##1 = *(const f4v*)(_p + 4); \
    R##2 = *(const f4v*)(_p + (size_t)64 * GK); \
    R##3 = *(const f4v*)(_p + (size_t)64 * GK + 4); \
    __builtin_amdgcn_sched_barrier(0); \
  } while (0)

#define AWRITE(R, ALB) do { \
    u16x8 _wa, _wb; \
    _wa[0]=f2bf(R##0[0]); _wa[1]=f2bf(R##0[1]); _wa[2]=f2bf(R##0[2]); _wa[3]=f2bf(R##0[3]); \
    _wa[4]=f2bf(R##1[0]); _wa[5]=f2bf(R##1[1]); _wa[6]=f2bf(R##1[2]); _wa[7]=f2bf(R##1[3]); \
    _wb[0]=f2bf(R##2[0]); _wb[1]=f2bf(R##2[1]); _wb[2]=f2bf(R##2[2]); _wb[3]=f2bf(R##2[3]); \
    _wb[4]=f2bf(R##3[0]); _wb[5]=f2bf(R##3[1]); _wb[6]=f2bf(R##3[2]); _wb[7]=f2bf(R##3[3]); \
    *(u16x8*)(lds + (ALB) + awoff) = _wa; \
    *(u16x8*)(lds + (ALB) + 4096 + awoff) = _wb; \
  } while (0)

#define VM6 do { asm volatile("s_waitcnt vmcnt(6)" ::: "memory"); __builtin_amdgcn_sched_barrier(0); } while (0)
#define VM4 do { asm volatile("s_waitcnt vmcnt(4)" ::: "memory"); __builtin_amdgcn_sched_barrier(0); } while (0)

#define PHASE(ABASE, BBASE, Q, FIRSTB, ...) do { \
    bf16x8 a00, a01, a10, a11; \
    if (FIRSTB) { \
        LDB8(b00, (BBASE), 0, 0); LDB8(b01, (BBASE), 0, 1); \
        LDB8(b10, (BBASE), 1, 0); LDB8(b11, (BBASE), 1, 1); \
        LDB8(b20, (BBASE), 2, 0); LDB8(b21, (BBASE), 2, 1); \
        LDB8(b30, (BBASE), 3, 0); LDB8(b31, (BBASE), 3, 1); \
    } \
    LDA8(a00, (ABASE), 2 * (Q), 0);     LDA8(a01, (ABASE), 2 * (Q), 1); \
    LDA8(a10, (ABASE), 2 * (Q) + 1, 0); LDA8(a11, (ABASE), 2 * (Q) + 1, 1); \
    __VA_ARGS__; \
    __builtin_amdgcn_s_barrier(); \
    asm volatile("s_waitcnt lgkmcnt(0)" ::: "memory"); \
    __builtin_amdgcn_sched_barrier(0); \
    __builtin_amdgcn_s_setprio(1); \
    acc[2*(Q)  ][0] = MFMA16(a00, b00, acc[2*(Q)  ][0]); \
    acc[2*(Q)  ][0] = MFMA16(a01, b01, acc[2*(Q)  ][0]); \
    acc[2*(Q)  ][1] = MFMA16(a00, b10, acc[2*(Q)  ][1]); \
    acc[2*(Q)  ][1] = MFMA16(a01, b11, acc[2*(Q)  ][1]); \
    acc[2*(Q)  ][2] = MFMA16(a00, b20, acc[2*(Q)  ][2]); \
    acc[2*(Q)  ][2] = MFMA16(a01, b21, acc[2*(Q)  ][2]); \
    acc[2*(Q)  ][3] = MFMA16(a00, b30, acc[2*(Q)  ][3]); \
    acc[2*(Q)  ][3] = MFMA16(a01, b31, acc[2*(Q)  ][3]); \
    acc[2*(Q)+1][0] = MFMA16(a10, b00, acc[2*(Q)+1][0]); \
    acc[2*(Q)+1][0] = MFMA16(a11, b01, acc[2*(Q)+1][0]); \
    acc[2*(Q)+1][1] = MFMA16(a10, b10, acc[2*(Q)+1][1]); \
    acc[2*(Q)+1][1] = MFMA16(a11, b11, acc[2*(Q)+1][1]); \
    acc[2*(Q)+1][2] = MFMA16(a10, b20, acc[2*(Q)+1][2]); \
    acc[2*(Q)+1][2] = MFMA16(a11, b21, acc[2*(Q)+1][2]); \
    acc[2*(Q)+1][3] = MFMA16(a10, b30, acc[2*(Q)+1][3]); \
    acc[2*(Q)+1][3] = MFMA16(a11, b31, acc[2*(Q)+1][3]); \
    __builtin_amdgcn_s_setprio(0); \
    __builtin_amdgcn_sched_barrier(0); \
    __builtin_amdgcn_s_barrier(); \
  } while (0)

__global__ __launch_bounds__(512, 2) void gemm256(
    const float* __restrict__ A32,
    const unsigned short* __restrict__ Bt,
    const float* __restrict__ Dc,
    const float* __restrict__ avec,
    const float* __restrict__ w3,
    const float* __restrict__ tvec,
    float* __restrict__ partial) {
    extern __shared__ unsigned short lds[];
    const int XA = 0, XB = 16384, YA = 32768, YB = 49152;

    int nwg = gridDim.x;
    int bid = blockIdx.x;
    int q8 = nwg >> 3;
    int wg = (bid & 7) * q8 + (bid >> 3);   // bijective XCD swizzle (nwg % 8 == 0)
    int rb = wg >> 3, cb = wg & 7;

    int tid = threadIdx.x;
    int wid = tid >> 6, lane = tid & 63;
    int wr = wid >> 2, wc = wid & 3;
    int l15 = lane & 15, lhi = lane >> 4;
    int rr = lane >> 3;        // 0..7
    int cch = lane & 7;        // chunk position
    int gq = (cch ^ rr) << 3;  // pre-swizzled global col offset (elements)
    int awoff = (wid << 9) + (rr << 6) + (cch << 3);  // ushort offset of A ds_write

    int arow = rb << 8;
    int brow = cb << 8;

    f32x4 acc[8][4];
#pragma unroll
    for (int i = 0; i < 8; i++)
#pragma unroll
        for (int j = 0; j < 4; j++) acc[i][j] = (f32x4)0.f;

    bf16x8 b00, b01, b10, b11, b20, b21, b30, b31;
    f4v Ra0, Ra1, Ra2, Ra3, Rb0, Rb1, Rb2, Rb3;

    // ---- prologue ----
    ALOAD(Ra, arow, 0);            // A8 in flight
    ALOAD(Rb, arow + 128, 0);
    STB(brow, 0, XB);  STB(brow + 128, 0, XB + 8192);    // XB (tile0)
    STB(brow, 64, YB); STB(brow + 128, 64, YB + 8192);   // YB (tile1)
    asm volatile("s_waitcnt vmcnt(8)" ::: "memory");     // A8 done; B8 may remain
    __builtin_amdgcn_sched_barrier(0);
    AWRITE(Ra, XA); AWRITE(Rb, XA + 8192);
    asm volatile("s_waitcnt vmcnt(4)" ::: "memory");     // XB done; YB4 outstanding
    asm volatile("s_waitcnt lgkmcnt(0)" ::: "memory");   // A ds_writes visible
    __builtin_amdgcn_sched_barrier(0);
    __builtin_amdgcn_s_barrier();

    // steady-state invariant at iteration top: outstanding VMEM = YB4;
    // XA/XB fully staged & visible.
    for (int it = 0; it < 16; ++it) {
        int k1 = ((it << 1) + 1) << 6;
        int k2 = (((it << 1) + 2) << 6) & 2047;  // dummy (unused) on last iter
        int k3 = (((it << 1) + 3) << 6) & 2047;
        PHASE(XA, XB, 0, 1, ALOAD(Ra, arow, k1));
        PHASE(XA, XB, 1, 0, ALOAD(Rb, arow + 128, k1));
        PHASE(XA, XB, 2, 0, { STB(brow, k2, XB);        VM6; AWRITE(Ra, YA); });
        PHASE(XA, XB, 3, 0, { STB(brow + 128, k2, XB + 8192); VM4; AWRITE(Rb, YA + 8192); });
        PHASE(YA, YB, 0, 1, ALOAD(Ra, arow, k2));
        PHASE(YA, YB, 1, 0, ALOAD(Rb, arow + 128, k2));
        PHASE(YA, YB, 2, 0, { STB(brow, k3, YB);        VM6; AWRITE(Ra, XA); });
        PHASE(YA, YB, 3, 0, { STB(brow + 128, k3, YB + 8192); VM4; AWRITE(Rb, XA + 8192); });
    }

    // ---- epilogue: fused tanh-dot partial scores ----
    int gcolb = (cb << 8) + (wc << 6) + l15;
    int bb = rb >> 3;   // 2048 rows per batch, 256 rows per rb
    float Dco[4], w3o[4], tv[4];
#pragma unroll
    for (int ni = 0; ni < 4; ++ni) {
        int o = gcolb + (ni << 4);
        Dco[ni] = Dc[(bb << 11) + o];
        w3o[ni] = w3[o];
        tv[ni] = tvec[o];
    }
    float* red = (float*)(lds + 65536);  // [256][4]
#pragma unroll
    for (int mi = 0; mi < 8; ++mi) {
#pragma unroll
        for (int j = 0; j < 4; ++j) {
            int rloc = (wr << 7) + (mi << 4) + (lhi << 2) + j;
            float av = avec[(rb << 8) + rloc];
            float s = 0.f;
#pragma unroll
            for (int ni = 0; ni < 4; ++ni) {
                float x = acc[mi][ni][j] + Dco[ni] + av * w3o[ni];
                x = fminf(fmaxf(x, -15.f), 15.f);
                float e = __expf(2.f * x);
                s += ((e - 1.f) / (e + 1.f)) * tv[ni];
            }
#pragma unroll
            for (int off2 = 1; off2 < 16; off2 <<= 1) s += __shfl_xor(s, off2);
            if (l15 == 0) red[(rloc << 2) + wc] = s;
        }
    }
    __syncthreads();
    if (tid < 256) {
        partial[(size_t)((rb << 8) + tid) * 8 + cb] =
            red[(tid << 2)] + red[(tid << 2) + 1] + red[(tid << 2) + 2] + red[(tid << 2) + 3];
    }
}

// ---------- sum 8 partials per row -> scores (parallel) ----------
__global__ __launch_bounds__(256) void sum_partial_kernel(
    const float* __restrict__ partial, float* __restrict__ scores) {
    int i = blockIdx.x * 256 + threadIdx.x;
    const f4v* p = (const f4v*)(partial + (size_t)i * 8);
    f4v a = p[0], b = p[1];
    scores[i] = a[0] + a[1] + a[2] + a[3] + b[0] + b[1] + b[2] + b[3];
}

// ---------- query softmax (alphas only) ----------
__global__ void softmax_q_alphas(const float* __restrict__ partial_q,
                                 const int* __restrict__ q_mask,
                                 float* __restrict__ out_qalphas) {
    int b = blockIdx.x, tid = threadIdx.x;  // 64 threads
    float s = 0.f;
    const float* p = partial_q + (size_t)(b * 64 + tid) * NCB;
#pragma unroll
    for (int c = 0; c < 16; c++) s += p[c];
    if (q_mask[b * 64 + tid] == 0) s = -INFINITY;
    float m = s;
    for (int off = 1; off < 64; off <<= 1) m = fmaxf(m, __shfl_xor(m, off));
    float e = (s == -INFINITY) ? 0.f : __expf(s - m);
    float sum = e;
    for (int off = 1; off < 64; off <<= 1) sum += __shfl_xor(sum, off);
    out_qalphas[b * 64 + tid] = e / sum;
}

// ---------- q_context = q_alphas @ q_value ----------
__global__ __launch_bounds__(256) void qctx_kernel(
    const float* __restrict__ qal, const float* __restrict__ q_value,
    float* __restrict__ qctx) {
    int b = blockIdx.x, dc = blockIdx.y, tid = threadIdx.x;
    __shared__ float sal[64];
    if (tid < 64) sal[tid] = qal[b * 64 + tid];
    __syncthreads();
    int d = (dc << 8) + tid;
    float acc = 0.f;
    for (int l = 0; l < 64; l++) {
        float al = sal[l];
        if (al != 0.f) acc += al * q_value[((size_t)(b * 64 + l) << 11) + d];
    }
    qctx[(b << 11) + d] = acc;
}

// ---------- text softmax (reads summed scores) ----------
__global__ __launch_bounds__(256) void softmax_t_kernel(
    const float* __restrict__ scores,
    const int* __restrict__ mask,
    float* __restrict__ out_alphas) {
    int b = blockIdx.x, tid = threadIdx.x;
    int wave = tid >> 6, lane = tid & 63;
    __shared__ float sred[4];
    float sc[8];
    float lm = -INFINITY;
#pragma unroll
    for (int i = 0; i < 8; i++) {
        int l = tid + (i << 8);
        float s = scores[b * 2048 + l];
        if (mask[b * 2048 + l] == 0) s = -INFINITY;
        sc[i] = s;
        lm = fmaxf(lm, s);
    }
    for (int off = 1; off < 64; off <<= 1) lm = fmaxf(lm, __shfl_xor(lm, off));
    if (lane == 0) sred[wave] = lm;
    __syncthreads();
    float m = fmaxf(fmaxf(sred[0], sred[1]), fmaxf(sred[2], sred[3]));
    float ee[8];
    float ls = 0.f;
#pragma unroll
    for (int i = 0; i < 8; i++) {
        ee[i] = (sc[i] == -INFINITY) ? 0.f : __expf(sc[i] - m);
        ls += ee[i];
    }
    for (int off = 1; off < 64; off <<= 1) ls += __shfl_xor(ls, off);
    __syncthreads();
    if (lane == 0) sred[wave] = ls;
    __syncthreads();
    float S = sred[0] + sred[1] + sred[2] + sred[3];
    float inv = 1.f / S;
#pragma unroll
    for (int i = 0; i < 8; i++)
        out_alphas[b * 2048 + tid + (i << 8)] = ee[i] * inv;
}

// ---------- context = alphas @ value ----------
__global__ __launch_bounds__(256) void ctx_partial_kernel(
    const float* __restrict__ alphas,
    const float* __restrict__ value,
    float* __restrict__ pctx) {
    int b = blockIdx.x, lc = blockIdx.y, tid = threadIdx.x;
    __shared__ float sa[128];
    if (tid < 128) sa[tid] = alphas[(b << 11) + (lc << 7) + tid];
    __syncthreads();
    f4v a0 = (f4v)0.f, a1 = (f4v)0.f;
    const float* vb = value + ((size_t)((b << 11) + (lc << 7)) << 11);
    for (int l = 0; l < 128; l++) {
        float al = sa[l];
        if (al != 0.f) {  // block-uniform branch; masked rows skipped
            const f4v* vr = (const f4v*)(vb + ((size_t)l << 11));
            a0 += al * vr[tid];
            a1 += al * vr[tid + 256];
        }
    }
    f4v* p = (f4v*)(pctx + ((size_t)((b << 4) + lc) << 11));
    p[tid] = a0;
    p[tid + 256] = a1;
}

__global__ __launch_bounds__(256) void ctx_reduce_kernel(
    const float* __restrict__ pctx, float* __restrict__ out_ctx) {
    int b = blockIdx.x, half = blockIdx.y, tid = threadIdx.x;
    int d4 = (half << 8) + tid;
    f4v s = (f4v)0.f;
#pragma unroll
    for (int lc = 0; lc < 16; lc++)
        s += ((const f4v*)(pctx + ((size_t)((b << 4) + lc) << 11)))[d4];
    ((f4v*)(out_ctx + ((size_t)b << 11)))[d4] = s;
}

// ---------- losses ----------
__global__ void loss_part_kernel(const float* __restrict__ qs, const float* __restrict__ qa,
                                 const float* __restrict__ ts, const float* __restrict__ ta,
                                 float* __restrict__ parts) {
    int blk = blockIdx.x, tid = threadIdx.x;  // 128 threads
    int wave = tid >> 6, lane = tid & 63;
    __shared__ float sred[2];
    float s = 0.f;
    if (blk == 0) {
        if (tid < 64) {
            float m = INFINITY;
#pragma unroll
            for (int b = 0; b < 16; ++b) {
                m = fminf(m, qs[(b << 6) + tid]);
                m = fminf(m, qa[(b << 6) + tid]);
            }
            s = m;
        }
    } else {
        int l = ((blk - 1) << 7) + tid;
        float m = INFINITY;
#pragma unroll
        for (int b = 0; b < 16; ++b) {
            m = fminf(m, ts[(b << 11) + l]);
            m = fminf(m, ta[(b << 11) + l]);
        }
        s = m;
    }
    for (int off = 1; off < 64; off <<= 1) s += __shfl_xor(s, off);
    if (lane == 0) sred[wave] = s;
    __syncthreads();
    if (tid == 0) parts[blk] = sred[0] + sred[1];
}

__global__ void loss_final_kernel(const float* __restrict__ parts,
                                  float* __restrict__ out_tl, float* __restrict__ out_ql) {
    if (threadIdx.x == 0) {
        *out_ql = parts[0];
        float t = 0.f;
        for (int i = 1; i <= 16; ++i) t += parts[i];
        *out_tl = t;
    }
}

extern "C" void kernel_launch(void* const* d_in, const int* in_sizes, int n_in,
                              void* d_out, int out_size, void* d_ws, size_t ws_size,
                              hipStream_t stream) {
    const float* query          = (const float*)d_in[0];
    const float* key            = (const float*)d_in[1];
    const float* value          = (const float*)d_in[2];
    const int*   mask           = (const int*)d_in[3];
    const float* q_key          = (const float*)d_in[4];
    const float* q_value        = (const float*)d_in[5];
    const int*   q_mask         = (const int*)d_in[6];
    const float* alphas_state   = (const float*)d_in[7];
    const float* q_alphas_state = (const float*)d_in[8];
    const float* W_q            = (const float*)d_in[9];
    const float* b_q            = (const float*)d_in[10];
    const float* W_t            = (const float*)d_in[11];
    const float* b_t            = (const float*)d_in[12];
    const float* query_other    = (const float*)d_in[13];
    const float* text_other     = (const float*)d_in[14];

    float* out        = (float*)d_out;
    float* out_ctx     = out;            // 16*2048
    float* out_alphas  = out + 32768;    // 16*2048
    float* out_qalphas = out + 65536;    // 16*64
    float* out_tloss   = out + 66560;
    float* out_qloss   = out + 66561;

    char* w = (char*)d_ws;
    size_t off = 0;
    auto alloc = [&](size_t bytes) -> char* {
        char* p = w + off;
        off += (bytes + 255) & ~(size_t)255;
        return p;
    };
    unsigned short* Wtk  = (unsigned short*)alloc(2048ull * 2048 * 2);
    unsigned short* Wqk  = (unsigned short*)alloc(2048ull * 2048 * 2);
    unsigned short* qkb  = (unsigned short*)alloc(1024ull * 2048 * 2);
    float* partial_t     = (float*)alloc(32768ull * 8 * 4);
    float* scores_t      = (float*)alloc(32768ull * 4);
    float* partial_q     = (float*)alloc(1024ull * NCB * 4);
    float* Dq            = (float*)alloc(16 * 2048 * 4);
    float* Dt            = (float*)alloc(16 * 2048 * 4);
    float* qctx          = (float*)alloc(16 * 2048 * 4);
    float* w3q           = (float*)alloc(2048 * 4);
    float* w3t           = (float*)alloc(2048 * 4);
    float* pctx          = (float*)alloc(16ull * 16 * 2048 * 4);
    float* lparts        = (float*)alloc(32 * 4);

    hipFuncSetAttribute((const void*)gemm256,
                        hipFuncAttributeMaxDynamicSharedMemorySize, 135168);

    // conversions + constants
    cvt_w_kernel<<<2048, 256, 0, stream>>>(W_t, 5121, Wtk);
    cvt_w_kernel<<<2048, 256, 0, stream>>>(W_q, 3073, Wqk);
    cvt_flat_kernel<<<1024, 256, 0, stream>>>(q_key, qkb, 1024l * 2048);
    extract_w3_kernel<<<8, 256, 0, stream>>>(W_q, W_t, w3q, w3t);
    dconst_kernel<1024><<<512, 256, 0, stream>>>(W_q, 3073, b_q, query, nullptr, Dq);

    // query-side GEMM + softmax + context
    gemm_score<6><<<128, 256, 0, stream>>>(qkb, Wqk, Dq, q_alphas_state, w3q,
                                           query_other, partial_q, 0);
    softmax_q_alphas<<<16, 64, 0, stream>>>(partial_q, q_mask, out_qalphas);
    qctx_kernel<<<dim3(16, 8), 256, 0, stream>>>(out_qalphas, q_value, qctx);

    // text-side constants, then fused-cvt GEMM over all 32768 rows
    dconst_kernel<3072><<<512, 256, 0, stream>>>(W_t, 5121, b_t, query, qctx, Dt);
    gemm256<<<1024, 512, 135168, stream>>>(key, Wtk, Dt, alphas_state, w3t,
                                           text_other, partial_t);

    sum_partial_kernel<<<128, 256, 0, stream>>>(partial_t, scores_t);
    softmax_t_kernel<<<16, 256, 0, stream>>>(scores_t, mask, out_alphas);
    ctx_partial_kernel<<<dim3(16, 16), 256, 0, stream>>>(out_alphas, value, pctx);
    ctx_reduce_kernel<<<dim3(16, 2), 256, 0, stream>>>(pctx, out_ctx);
    loss_part_kernel<<<17, 128, 0, stream>>>(q_alphas_state, out_qalphas,
                                             alphas_state, out_alphas, lparts);
    loss_final_kernel<<<1, 64, 0, stream>>>(lparts, out_tloss, out_qloss);
}

// Round 5
// 694.834 us; speedup vs baseline: 1.0692x; 1.0692x over previous
//
#include <hip/hip_runtime.h>
#include <hip/hip_bf16.h>
#include <math.h>

#define GK 2048
#define NCB 16   // query-side partial stride

typedef __attribute__((ext_vector_type(8))) short bf16x8;
typedef __attribute__((ext_vector_type(4))) float f32x4;
typedef __attribute__((ext_vector_type(4))) float f4v;
typedef __attribute__((ext_vector_type(4))) unsigned short u16x4;
typedef __attribute__((ext_vector_type(8))) unsigned short u16x8;

__device__ __forceinline__ unsigned short f2bf(float x) {
    unsigned int u = __float_as_uint(x);
    u += 0x7fffu + ((u >> 16) & 1u);
    return (unsigned short)(u >> 16);
}

__device__ __forceinline__ void gl_lds16(const void* g, void* l) {
    __builtin_amdgcn_global_load_lds(
        (const __attribute__((address_space(1))) unsigned int*)g,
        (__attribute__((address_space(3))) unsigned int*)l, 16, 0, 0);
}

// ---------- merged prep: cvt W_t, cvt W_q, cvt q_key, extract w3 ----------
__global__ void prep_kernel(const float* __restrict__ Wt, const float* __restrict__ Wq,
                            const float* __restrict__ q_key,
                            unsigned short* __restrict__ Wtk, unsigned short* __restrict__ Wqk,
                            unsigned short* __restrict__ qkb,
                            float* __restrict__ w3q, float* __restrict__ w3t) {
    int b = blockIdx.x, tid = threadIdx.x;
    if (b < 2048) {
        const float* s = Wt + (size_t)b * 5121;
        unsigned short* d = Wtk + (size_t)b * 2048;
#pragma unroll
        for (int k = 0; k < 8; k++) { int c = tid + (k << 8); d[c] = f2bf(s[c]); }
    } else if (b < 4096) {
        int o = b - 2048;
        const float* s = Wq + (size_t)o * 3073;
        unsigned short* d = Wqk + (size_t)o * 2048;
#pragma unroll
        for (int k = 0; k < 8; k++) { int c = tid + (k << 8); d[c] = f2bf(s[c]); }
    } else if (b < 5120) {
        long i = ((long)(b - 4096) * 256 + tid) * 8;
        f4v a = *(const f4v*)(q_key + i);
        f4v c = *(const f4v*)(q_key + i + 4);
        u16x4 r0, r1;
        r0[0] = f2bf(a[0]); r0[1] = f2bf(a[1]); r0[2] = f2bf(a[2]); r0[3] = f2bf(a[3]);
        r1[0] = f2bf(c[0]); r1[1] = f2bf(c[1]); r1[2] = f2bf(c[2]); r1[3] = f2bf(c[3]);
        *(u16x4*)(qkb + i) = r0;
        *(u16x4*)(qkb + i + 4) = r1;
    } else {
        int o = (b - 5120) * 256 + tid;
        w3q[o] = Wq[(size_t)o * 3073 + 3072];
        w3t[o] = Wt[(size_t)o * 5121 + 3072];
    }
}

// ---------- per-batch constant D[b][o] ----------
template <int KLEN>
__global__ __launch_bounds__(256) void dconst_kernel(
    const float* __restrict__ W, long ldw,
    const float* __restrict__ bias,
    const float* __restrict__ query,
    const float* __restrict__ qctx,
    float* __restrict__ Dout) {
    int tid = threadIdx.x;
    int wave = tid >> 6, lane = tid & 63;
    int o = blockIdx.x * 4 + wave;
    const float* wrow = W + (size_t)o * ldw + 2048;
    float acc[16];
#pragma unroll
    for (int b2 = 0; b2 < 16; b2++) acc[b2] = 0.f;
    for (int i = lane; i < KLEN; i += 64) {
        if (KLEN == 1024 || i < 1024) {
            float wv = wrow[i];
            const float* qp = query + i;
#pragma unroll
            for (int b2 = 0; b2 < 16; b2++) acc[b2] += wv * qp[b2 * 1024];
        } else {
            float wv = wrow[i + 1];  // skip alphas column at 3072
            const float* cp = qctx + (i - 1024);
#pragma unroll
            for (int b2 = 0; b2 < 16; b2++) acc[b2] += wv * cp[b2 * 2048];
        }
    }
#pragma unroll
    for (int b2 = 0; b2 < 16; b2++) {
        float v = acc[b2];
        for (int off = 1; off < 64; off <<= 1) v += __shfl_xor(v, off);
        if (lane == 0) Dout[(b2 << 11) + o] = v + bias[o];
    }
}

// ---------- query-side fused GEMM (128x128 tile, m97 structure) ----------
template <int LOG_RPB>
__global__ __launch_bounds__(256) void gemm_score(
    const unsigned short* __restrict__ A,
    const unsigned short* __restrict__ Bt,
    const float* __restrict__ Dc,
    const float* __restrict__ avec,
    const float* __restrict__ w3,
    const float* __restrict__ tvec,
    float* __restrict__ partial,
    int row0) {
    __shared__ unsigned short As[128 * 32];
    __shared__ unsigned short Bs[128 * 32];
    __shared__ float red[128][2];

    int nwg = gridDim.x;
    int bid = blockIdx.x;
    int q8 = nwg >> 3;
    int wg = (bid & 7) * q8 + (bid >> 3);
    int rb = wg >> 4, cb = wg & 15;

    int tid = threadIdx.x;
    int wave = tid >> 6, lane = tid & 63;
    int wr = wave >> 1, wc = wave & 1;
    int l15 = lane & 15, lhi = lane >> 4;

    const unsigned short* Ab = A + (size_t)rb * 128 * GK;
    const unsigned short* Bb = Bt + (size_t)cb * 128 * GK;

    int r0 = tid >> 2, c0 = (tid & 3) << 3;

    f32x4 acc[4][4];
#pragma unroll
    for (int i = 0; i < 4; i++)
#pragma unroll
        for (int j = 0; j < 4; j++) acc[i][j] = (f32x4)0.f;

    unsigned short* AsW0 = As + (wave << 9);
    unsigned short* AsW1 = As + 2048 + (wave << 9);
    unsigned short* BsW0 = Bs + (wave << 9);
    unsigned short* BsW1 = Bs + 2048 + (wave << 9);

    for (int k0 = 0; k0 < GK; k0 += 32) {
        __syncthreads();
        gl_lds16(Ab + (size_t)r0 * GK + k0 + c0, AsW0);
        gl_lds16(Ab + (size_t)(r0 + 64) * GK + k0 + c0, AsW1);
        gl_lds16(Bb + (size_t)r0 * GK + k0 + c0, BsW0);
        gl_lds16(Bb + (size_t)(r0 + 64) * GK + k0 + c0, BsW1);
        __syncthreads();
        bf16x8 a[4], b[4];
#pragma unroll
        for (int mi = 0; mi < 4; mi++)
            a[mi] = *(const bf16x8*)(As + (((wr << 6) + (mi << 4) + l15) << 5) + (lhi << 3));
#pragma unroll
        for (int ni = 0; ni < 4; ni++)
            b[ni] = *(const bf16x8*)(Bs + (((wc << 6) + (ni << 4) + l15) << 5) + (lhi << 3));
#pragma unroll
        for (int mi = 0; mi < 4; mi++)
#pragma unroll
            for (int ni = 0; ni < 4; ni++)
                acc[mi][ni] = __builtin_amdgcn_mfma_f32_16x16x32_bf16(a[mi], b[ni], acc[mi][ni], 0, 0, 0);
    }

    int grow_base = row0 + (rb << 7) + (wr << 6);
    int bb = grow_base >> LOG_RPB;
    int gcol = (cb << 7) + (wc << 6) + l15;
    float Dco[4], w3o[4], tv[4];
#pragma unroll
    for (int ni = 0; ni < 4; ni++) {
        int o = gcol + (ni << 4);
        Dco[ni] = Dc[(bb << 11) + o];
        w3o[ni] = w3[o];
        tv[ni] = tvec[o];
    }
#pragma unroll
    for (int mi = 0; mi < 4; mi++) {
#pragma unroll
        for (int j = 0; j < 4; j++) {
            int rloc = (mi << 4) + (lhi << 2) + j;
            float av = avec[grow_base + rloc];
            float s = 0.f;
#pragma unroll
            for (int ni = 0; ni < 4; ni++) {
                float x = acc[mi][ni][j] + Dco[ni] + av * w3o[ni];
                x = fminf(fmaxf(x, -15.f), 15.f);
                float e = __expf(2.f * x);
                s += ((e - 1.f) / (e + 1.f)) * tv[ni];
            }
#pragma unroll
            for (int off = 1; off < 16; off <<= 1) s += __shfl_xor(s, off);
            if (l15 == 0) red[(wr << 6) + rloc][wc] = s;
        }
    }
    __syncthreads();
    if (tid < 128) {
        partial[(size_t)(row0 + (rb << 7) + tid) * NCB + cb] = red[tid][0] + red[tid][1];
    }
}

// ---------- text-side 256x256 8-phase GEMM, A = f32 reg-staged (fused cvt) ----------
// LDS (ushort units): XA=0, XB=16384, YA=32768, YB=49152, red @65536 (float[256][4])
// Swizzle: LDS 16B-chunk position p of row r holds global chunk p ^ (r&7).
// Staggered A staging: Ra (half-panel, 16 f32 regs) load ph1 -> cvt+write ph3;
// Rb load ph3 (after Ra freed) -> cvt+write ph4. Peak staging regs = 16.
#define MFMA16(A, B, C) __builtin_amdgcn_mfma_f32_16x16x32_bf16(A, B, C, 0, 0, 0)

#define LDA8(dst, ABASE, MI, KK) { \
    int _r = (wr << 7) + ((MI) << 4) + l15; \
    dst = *(const bf16x8*)(lds + (ABASE) + (_r << 6) + (((((KK) << 2) | lhi) ^ (_r & 7)) << 3)); }

#define LDB8(dst, BBASE, NI, KK) { \
    int _r = (wc << 6) + ((NI) << 4) + l15; \
    dst = *(const bf16x8*)(lds + (BBASE) + (_r << 6) + (((((KK) << 2) | lhi) ^ (_r & 7)) << 3)); }

// B staging: global_load_lds, pre-swizzled global source, linear LDS dest (2 gl_lds)
#define STB(GR0, K0, LB) do { \
    gl_lds16(Bt + (size_t)((GR0) + (wid << 3) + rr) * GK + (K0) + ((cch ^ rr) << 3), lds + (LB) + (wid << 9)); \
    gl_lds16(Bt + (size_t)((GR0) + 64 + (wid << 3) + rr) * GK + (K0) + ((cch ^ rr) << 3), lds + (LB) + 4096 + (wid << 9)); \
  } while (0)

// A staging half-panel: 4 f32 dwordx4 loads (16 VGPR), 128 rows x 64 cols.
// Lane covers row (wid*8+rr) and row+64, global chunk cch^rr (8 f32 each).
#define ALOAD(R, GR0, K0) do { \
    const float* _p = A32 + (size_t)((GR0) + (wid << 3) + rr) * GK + (K0) + gq; \
    R##0 = *(const f4v*)_p; \
    R##1 = *(const f4v*)(_p + 4); \
    R##2 = *(const f4v*)(_p + (size_t)64 * GK); \
    R##3 = *(const f4v*)(_p + (size_t)64 * GK + 4); \
    __builtin_amdgcn_sched_barrier(0); \
  } while (0)

// cvt + ds_write of one half-panel; stored LDS chunk = cch (pre-swizzled load)
#define CVTAW(R, ALB) do { \
    u16x8 _wa, _wb; \
    _wa[0]=f2bf(R##0[0]); _wa[1]=f2bf(R##0[1]); _wa[2]=f2bf(R##0[2]); _wa[3]=f2bf(R##0[3]); \
    _wa[4]=f2bf(R##1[0]); _wa[5]=f2bf(R##1[1]); _wa[6]=f2bf(R##1[2]); _wa[7]=f2bf(R##1[3]); \
    _wb[0]=f2bf(R##2[0]); _wb[1]=f2bf(R##2[1]); _wb[2]=f2bf(R##2[2]); _wb[3]=f2bf(R##2[3]); \
    _wb[4]=f2bf(R##3[0]); _wb[5]=f2bf(R##3[1]); _wb[6]=f2bf(R##3[2]); _wb[7]=f2bf(R##3[3]); \
    *(u16x8*)(lds + (ALB) + awoff) = _wa; \
    *(u16x8*)(lds + (ALB) + 4096 + awoff) = _wb; \
    __builtin_amdgcn_sched_barrier(0); \
  } while (0)

#define VM2 do { asm volatile("s_waitcnt vmcnt(2)" ::: "memory"); __builtin_amdgcn_sched_barrier(0); } while (0)

#define PHASE(ABASE, BBASE, Q, FIRSTB, ...) do { \
    bf16x8 a00, a01, a10, a11; \
    if (FIRSTB) { \
        LDB8(b00, (BBASE), 0, 0); LDB8(b01, (BBASE), 0, 1); \
        LDB8(b10, (BBASE), 1, 0); LDB8(b11, (BBASE), 1, 1); \
        LDB8(b20, (BBASE), 2, 0); LDB8(b21, (BBASE), 2, 1); \
        LDB8(b30, (BBASE), 3, 0); LDB8(b31, (BBASE), 3, 1); \
    } \
    LDA8(a00, (ABASE), 2 * (Q), 0);     LDA8(a01, (ABASE), 2 * (Q), 1); \
    LDA8(a10, (ABASE), 2 * (Q) + 1, 0); LDA8(a11, (ABASE), 2 * (Q) + 1, 1); \
    __VA_ARGS__; \
    __builtin_amdgcn_s_barrier(); \
    asm volatile("s_waitcnt lgkmcnt(0)" ::: "memory"); \
    __builtin_amdgcn_sched_barrier(0); \
    __builtin_amdgcn_s_setprio(1); \
    acc[2*(Q)  ][0] = MFMA16(a00, b00, acc[2*(Q)  ][0]); \
    acc[2*(Q)  ][0] = MFMA16(a01, b01, acc[2*(Q)  ][0]); \
    acc[2*(Q)  ][1] = MFMA16(a00, b10, acc[2*(Q)  ][1]); \
    acc[2*(Q)  ][1] = MFMA16(a01, b11, acc[2*(Q)  ][1]); \
    acc[2*(Q)  ][2] = MFMA16(a00, b20, acc[2*(Q)  ][2]); \
    acc[2*(Q)  ][2] = MFMA16(a01, b21, acc[2*(Q)  ][2]); \
    acc[2*(Q)  ][3] = MFMA16(a00, b30, acc[2*(Q)  ][3]); \
    acc[2*(Q)  ][3] = MFMA16(a01, b31, acc[2*(Q)  ][3]); \
    acc[2*(Q)+1][0] = MFMA16(a10, b00, acc[2*(Q)+1][0]); \
    acc[2*(Q)+1][0] = MFMA16(a11, b01, acc[2*(Q)+1][0]); \
    acc[2*(Q)+1][1] = MFMA16(a10, b10, acc[2*(Q)+1][1]); \
    acc[2*(Q)+1][1] = MFMA16(a11, b11, acc[2*(Q)+1][1]); \
    acc[2*(Q)+1][2] = MFMA16(a10, b20, acc[2*(Q)+1][2]); \
    acc[2*(Q)+1][2] = MFMA16(a11, b21, acc[2*(Q)+1][2]); \
    acc[2*(Q)+1][3] = MFMA16(a10, b30, acc[2*(Q)+1][3]); \
    acc[2*(Q)+1][3] = MFMA16(a11, b31, acc[2*(Q)+1][3]); \
    __builtin_amdgcn_s_setprio(0); \
    __builtin_amdgcn_sched_barrier(0); \
    __builtin_amdgcn_s_barrier(); \
  } while (0)

__global__ __launch_bounds__(512, 2) void gemm256(
    const float* __restrict__ A32,
    const unsigned short* __restrict__ Bt,
    const float* __restrict__ Dc,
    const float* __restrict__ avec,
    const float* __restrict__ w3,
    const float* __restrict__ tvec,
    float* __restrict__ partial) {
    extern __shared__ unsigned short lds[];
    const int XA = 0, XB = 16384, YA = 32768, YB = 49152;

    int nwg = gridDim.x;
    int bid = blockIdx.x;
    int q8 = nwg >> 3;
    int wg = (bid & 7) * q8 + (bid >> 3);   // bijective XCD swizzle (nwg % 8 == 0)
    int rb = wg >> 3, cb = wg & 7;

    int tid = threadIdx.x;
    int wid = tid >> 6, lane = tid & 63;
    int wr = wid >> 2, wc = wid & 3;
    int l15 = lane & 15, lhi = lane >> 4;
    int rr = lane >> 3;        // 0..7
    int cch = lane & 7;        // chunk position
    int gq = (cch ^ rr) << 3;  // pre-swizzled global col offset (elements)
    int awoff = (wid << 9) + (rr << 6) + (cch << 3);  // ushort offset of A ds_write

    int arow = rb << 8;
    int brow = cb << 8;

    f32x4 acc[8][4];
#pragma unroll
    for (int i = 0; i < 8; i++)
#pragma unroll
        for (int j = 0; j < 4; j++) acc[i][j] = (f32x4)0.f;

    bf16x8 b00, b01, b10, b11, b20, b21, b30, b31;
    f4v Ra0, Ra1, Ra2, Ra3, Rb0, Rb1, Rb2, Rb3;

    // ---- prologue ----
    ALOAD(Ra, arow, 0);            // A tile0 rows 0-127
    ALOAD(Rb, arow + 128, 0);      // A tile0 rows 128-255
    STB(brow, 0, XB);  STB(brow + 128, 0, XB + 8192);    // B tile0
    STB(brow, 64, YB); STB(brow + 128, 64, YB + 8192);   // B tile1
    asm volatile("s_waitcnt vmcnt(8)" ::: "memory");     // Ra+Rb done
    __builtin_amdgcn_sched_barrier(0);
    CVTAW(Ra, XA); CVTAW(Rb, XA + 8192);
    asm volatile("s_waitcnt vmcnt(4)" ::: "memory");     // XB done; YB4 outstanding
    asm volatile("s_waitcnt lgkmcnt(0)" ::: "memory");   // A ds_writes landed
    __builtin_amdgcn_sched_barrier(0);
    __builtin_amdgcn_s_barrier();

    // vmcnt ledger (steady state, drains oldest-first):
    //  ph3 VM2: drains prev-YB.hi(2) + Ra(4); leaves new STB-XB.lo(2)
    //  ph4 VM2: drains STB-XB.lo(2) + Rb(4); leaves STB-XB.hi(2)
    //  ph7 VM2: drains STB-XB.hi(2) + Ra(4); leaves STB-YB.lo(2)
    //  ph8 VM2: drains STB-YB.lo(2) + Rb(4); leaves STB-YB.hi(2)
    // Every LDS slot completes >=1 barrier before its first read.
    for (int it = 0; it < 16; ++it) {
        int k1 = ((it << 1) + 1) << 6;
        int k2 = (((it << 1) + 2) << 6) & 2047;  // dummy (harmless) on last iter
        int k3 = (((it << 1) + 3) << 6) & 2047;
        PHASE(XA, XB, 0, 1, ALOAD(Ra, arow, k1));
        PHASE(XA, XB, 1, 0, {});
        PHASE(XA, XB, 2, 0, { STB(brow, k2, XB);              VM2; CVTAW(Ra, YA);        ALOAD(Rb, arow + 128, k1); });
        PHASE(XA, XB, 3, 0, { STB(brow + 128, k2, XB + 8192); VM2; CVTAW(Rb, YA + 8192); });
        PHASE(YA, YB, 0, 1, ALOAD(Ra, arow, k2));
        PHASE(YA, YB, 1, 0, {});
        PHASE(YA, YB, 2, 0, { STB(brow, k3, YB);              VM2; CVTAW(Ra, XA);        ALOAD(Rb, arow + 128, k2); });
        PHASE(YA, YB, 3, 0, { STB(brow + 128, k3, YB + 8192); VM2; CVTAW(Rb, XA + 8192); });
    }

    // ---- epilogue: fused tanh-dot partial scores ----
    int gcolb = (cb << 8) + (wc << 6) + l15;
    int bb = rb >> 3;   // 2048 rows per batch, 256 rows per rb
    float Dco[4], w3o[4], tv[4];
#pragma unroll
    for (int ni = 0; ni < 4; ++ni) {
        int o = gcolb + (ni << 4);
        Dco[ni] = Dc[(bb << 11) + o];
        w3o[ni] = w3[o];
        tv[ni] = tvec[o];
    }
    float* red = (float*)(lds + 65536);  // [256][4]
#pragma unroll
    for (int mi = 0; mi < 8; ++mi) {
#pragma unroll
        for (int j = 0; j < 4; ++j) {
            int rloc = (wr << 7) + (mi << 4) + (lhi << 2) + j;
            float av = avec[(rb << 8) + rloc];
            float s = 0.f;
#pragma unroll
            for (int ni = 0; ni < 4; ++ni) {
                float x = acc[mi][ni][j] + Dco[ni] + av * w3o[ni];
                x = fminf(fmaxf(x, -15.f), 15.f);
                float e = __expf(2.f * x);
                s += ((e - 1.f) / (e + 1.f)) * tv[ni];
            }
#pragma unroll
            for (int off2 = 1; off2 < 16; off2 <<= 1) s += __shfl_xor(s, off2);
            if (l15 == 0) red[(rloc << 2) + wc] = s;
        }
    }
    __syncthreads();
    if (tid < 256) {
        partial[(size_t)((rb << 8) + tid) * 8 + cb] =
            red[(tid << 2)] + red[(tid << 2) + 1] + red[(tid << 2) + 2] + red[(tid << 2) + 3];
    }
}

// ---------- query softmax + q_context (merged) ----------
__global__ __launch_bounds__(256) void softmax_q_kernel(
    const float* __restrict__ partial_q,
    const int* __restrict__ q_mask,
    const float* __restrict__ q_value,
    float* __restrict__ out_qalphas,
    float* __restrict__ qctx) {
    int b = blockIdx.x, tid = threadIdx.x;
    __shared__ float sal[64];
    if (tid < 64) {
        float s = 0.f;
        const float* p = partial_q + (size_t)(b * 64 + tid) * NCB;
#pragma unroll
        for (int c = 0; c < 16; c++) s += p[c];
        if (q_mask[b * 64 + tid] == 0) s = -INFINITY;
        float m = s;
        for (int off = 1; off < 64; off <<= 1) m = fmaxf(m, __shfl_xor(m, off));
        float e = (s == -INFINITY) ? 0.f : __expf(s - m);
        float sum = e;
        for (int off = 1; off < 64; off <<= 1) sum += __shfl_xor(sum, off);
        float a = e / sum;
        sal[tid] = a;
        out_qalphas[b * 64 + tid] = a;
    }
    __syncthreads();
    for (int d = tid; d < 2048; d += 256) {
        float acc = 0.f;
        for (int l = 0; l < 64; l++) {
            float al = sal[l];
            if (al != 0.f) acc += al * q_value[((size_t)(b * 64 + l)) * 2048 + d];
        }
        qctx[b * 2048 + d] = acc;
    }
}

// ---------- text softmax (stride-8 partials) ----------
__global__ __launch_bounds__(256) void softmax_t_kernel(
    const float* __restrict__ partial,
    const int* __restrict__ mask,
    float* __restrict__ out_alphas) {
    int b = blockIdx.x, tid = threadIdx.x;
    int wave = tid >> 6, lane = tid & 63;
    __shared__ float sred[4];
    float sc[8];
    float lm = -INFINITY;
#pragma unroll
    for (int i = 0; i < 8; i++) {
        int l = tid + (i << 8);
        const float* p = partial + (size_t)(b * 2048 + l) * 8;
        float s = 0.f;
#pragma unroll
        for (int c = 0; c < 8; c++) s += p[c];
        if (mask[b * 2048 + l] == 0) s = -INFINITY;
        sc[i] = s;
        lm = fmaxf(lm, s);
    }
    for (int off = 1; off < 64; off <<= 1) lm = fmaxf(lm, __shfl_xor(lm, off));
    if (lane == 0) sred[wave] = lm;
    __syncthreads();
    float m = fmaxf(fmaxf(sred[0], sred[1]), fmaxf(sred[2], sred[3]));
    float ee[8];
    float ls = 0.f;
#pragma unroll
    for (int i = 0; i < 8; i++) {
        ee[i] = (sc[i] == -INFINITY) ? 0.f : __expf(sc[i] - m);
        ls += ee[i];
    }
    for (int off = 1; off < 64; off <<= 1) ls += __shfl_xor(ls, off);
    __syncthreads();
    if (lane == 0) sred[wave] = ls;
    __syncthreads();
    float S = sred[0] + sred[1] + sred[2] + sred[3];
    float inv = 1.f / S;
#pragma unroll
    for (int i = 0; i < 8; i++)
        out_alphas[b * 2048 + tid + (i << 8)] = ee[i] * inv;
}

// ---------- context = alphas @ value ----------
__global__ __launch_bounds__(256) void ctx_partial_kernel(
    const float* __restrict__ alphas,
    const float* __restrict__ value,
    float* __restrict__ pctx) {
    int b = blockIdx.x, lc = blockIdx.y, tid = threadIdx.x;
    __shared__ float sa[128];
    if (tid < 128) sa[tid] = alphas[(b << 11) + (lc << 7) + tid];
    __syncthreads();
    f4v a0 = (f4v)0.f, a1 = (f4v)0.f;
    const float* vb = value + ((size_t)((b << 11) + (lc << 7)) << 11);
    for (int l = 0; l < 128; l++) {
        float al = sa[l];
        if (al != 0.f) {  // block-uniform branch; masked rows skipped
            const f4v* vr = (const f4v*)(vb + ((size_t)l << 11));
            a0 += al * vr[tid];
            a1 += al * vr[tid + 256];
        }
    }
    f4v* p = (f4v*)(pctx + ((size_t)((b << 4) + lc) << 11));
    p[tid] = a0;
    p[tid + 256] = a1;
}

__global__ __launch_bounds__(256) void ctx_reduce_kernel(
    const float* __restrict__ pctx, float* __restrict__ out_ctx) {
    int b = blockIdx.x, half = blockIdx.y, tid = threadIdx.x;
    int d4 = (half << 8) + tid;
    f4v s = (f4v)0.f;
#pragma unroll
    for (int lc = 0; lc < 16; lc++)
        s += ((const f4v*)(pctx + ((size_t)((b << 4) + lc) << 11)))[d4];
    ((f4v*)(out_ctx + ((size_t)b << 11)))[d4] = s;
}

// ---------- losses ----------
__global__ void loss_part_kernel(const float* __restrict__ qs, const float* __restrict__ qa,
                                 const float* __restrict__ ts, const float* __restrict__ ta,
                                 float* __restrict__ parts) {
    int blk = blockIdx.x, tid = threadIdx.x;  // 128 threads
    int wave = tid >> 6, lane = tid & 63;
    __shared__ float sred[2];
    float s = 0.f;
    if (blk == 0) {
        if (tid < 64) {
            float m = INFINITY;
#pragma unroll
            for (int b = 0; b < 16; ++b) {
                m = fminf(m, qs[(b << 6) + tid]);
                m = fminf(m, qa[(b << 6) + tid]);
            }
            s = m;
        }
    } else {
        int l = ((blk - 1) << 7) + tid;
        float m = INFINITY;
#pragma unroll
        for (int b = 0; b < 16; ++b) {
            m = fminf(m, ts[(b << 11) + l]);
            m = fminf(m, ta[(b << 11) + l]);
        }
        s = m;
    }
    for (int off = 1; off < 64; off <<= 1) s += __shfl_xor(s, off);
    if (lane == 0) sred[wave] = s;
    __syncthreads();
    if (tid == 0) parts[blk] = sred[0] + sred[1];
}

__global__ void loss_final_kernel(const float* __restrict__ parts,
                                  float* __restrict__ out_tl, float* __restrict__ out_ql) {
    if (threadIdx.x == 0) {
        *out_ql = parts[0];
        float t = 0.f;
        for (int i = 1; i <= 16; ++i) t += parts[i];
        *out_tl = t;
    }
}

extern "C" void kernel_launch(void* const* d_in, const int* in_sizes, int n_in,
                              void* d_out, int out_size, void* d_ws, size_t ws_size,
                              hipStream_t stream) {
    const float* query          = (const float*)d_in[0];
    const float* key            = (const float*)d_in[1];
    const float* value          = (const float*)d_in[2];
    const int*   mask           = (const int*)d_in[3];
    const float* q_key          = (const float*)d_in[4];
    const float* q_value        = (const float*)d_in[5];
    const int*   q_mask         = (const int*)d_in[6];
    const float* alphas_state   = (const float*)d_in[7];
    const float* q_alphas_state = (const float*)d_in[8];
    const float* W_q            = (const float*)d_in[9];
    const float* b_q            = (const float*)d_in[10];
    const float* W_t            = (const float*)d_in[11];
    const float* b_t            = (const float*)d_in[12];
    const float* query_other    = (const float*)d_in[13];
    const float* text_other     = (const float*)d_in[14];

    float* out        = (float*)d_out;
    float* out_ctx     = out;            // 16*2048
    float* out_alphas  = out + 32768;    // 16*2048
    float* out_qalphas = out + 65536;    // 16*64
    float* out_tloss   = out + 66560;
    float* out_qloss   = out + 66561;

    char* w = (char*)d_ws;
    size_t off = 0;
    auto alloc = [&](size_t bytes) -> char* {
        char* p = w + off;
        off += (bytes + 255) & ~(size_t)255;
        return p;
    };
    unsigned short* Wtk  = (unsigned short*)alloc(2048ull * 2048 * 2);
    unsigned short* Wqk  = (unsigned short*)alloc(2048ull * 2048 * 2);
    unsigned short* qkb  = (unsigned short*)alloc(1024ull * 2048 * 2);
    float* partial_t     = (float*)alloc(32768ull * 8 * 4);
    float* partial_q     = (float*)alloc(1024ull * NCB * 4);
    float* Dq            = (float*)alloc(16 * 2048 * 4);
    float* Dt            = (float*)alloc(16 * 2048 * 4);
    float* qctx          = (float*)alloc(16 * 2048 * 4);
    float* w3q           = (float*)alloc(2048 * 4);
    float* w3t           = (float*)alloc(2048 * 4);
    float* pctx          = (float*)alloc(16ull * 16 * 2048 * 4);
    float* lparts        = (float*)alloc(32 * 4);

    hipFuncSetAttribute((const void*)gemm256,
                        hipFuncAttributeMaxDynamicSharedMemorySize, 135168);

    // merged conversions
    prep_kernel<<<5128, 256, 0, stream>>>(W_t, W_q, q_key, Wtk, Wqk, qkb, w3q, w3t);
    dconst_kernel<1024><<<512, 256, 0, stream>>>(W_q, 3073, b_q, query, nullptr, Dq);

    // query-side GEMM + softmax + context
    gemm_score<6><<<128, 256, 0, stream>>>(qkb, Wqk, Dq, q_alphas_state, w3q,
                                           query_other, partial_q, 0);
    softmax_q_kernel<<<16, 256, 0, stream>>>(partial_q, q_mask, q_value, out_qalphas, qctx);

    // text-side constants, then fused-cvt GEMM over all 32768 rows
    dconst_kernel<3072><<<512, 256, 0, stream>>>(W_t, 5121, b_t, query, qctx, Dt);
    gemm256<<<1024, 512, 135168, stream>>>(key, Wtk, Dt, alphas_state, w3t,
                                           text_other, partial_t);

    softmax_t_kernel<<<16, 256, 0, stream>>>(partial_t, mask, out_alphas);
    ctx_partial_kernel<<<dim3(16, 16), 256, 0, stream>>>(out_alphas, value, pctx);
    ctx_reduce_kernel<<<dim3(16, 2), 256, 0, stream>>>(pctx, out_ctx);
    loss_part_kernel<<<17, 128, 0, stream>>>(q_alphas_state, out_qalphas,
                                             alphas_state, out_alphas, lparts);
    loss_final_kernel<<<1, 64, 0, stream>>>(lparts, out_tloss, out_qloss);
}

// Round 7
// 511.708 us; speedup vs baseline: 1.4518x; 1.3579x over previous
//
#include <hip/hip_runtime.h>
#include <hip/hip_bf16.h>
#include <math.h>

#define GK 2048
#define NCB 16   // query-side partial stride

typedef __attribute__((ext_vector_type(8))) short bf16x8;
typedef __attribute__((ext_vector_type(4))) float f32x4;
typedef __attribute__((ext_vector_type(4))) float f4v;
typedef __attribute__((ext_vector_type(4))) unsigned short u16x4;
typedef __attribute__((ext_vector_type(8))) unsigned short u16x8;

__device__ __forceinline__ unsigned short f2bf(float x) {
    unsigned int u = __float_as_uint(x);
    u += 0x7fffu + ((u >> 16) & 1u);
    return (unsigned short)(u >> 16);
}

__device__ __forceinline__ void gl_lds16(const void* g, void* l) {
    __builtin_amdgcn_global_load_lds(
        (const __attribute__((address_space(1))) unsigned int*)g,
        (__attribute__((address_space(3))) unsigned int*)l, 16, 0, 0);
}

// ---------- merged prep: cvt key, cvt W_t, cvt W_q, cvt q_key, extract w3 ----------
__global__ void prep_kernel(const float* __restrict__ Wt, const float* __restrict__ Wq,
                            const float* __restrict__ q_key, const float* __restrict__ key,
                            unsigned short* __restrict__ Wtk, unsigned short* __restrict__ Wqk,
                            unsigned short* __restrict__ qkb, unsigned short* __restrict__ keyb,
                            float* __restrict__ w3q, float* __restrict__ w3t) {
    int b = blockIdx.x, tid = threadIdx.x;
    if (b < 32768) {                       // key: one row (2048 f32) per block
        long i = ((long)b << 11) + (tid << 3);
        f4v a = *(const f4v*)(key + i);
        f4v c = *(const f4v*)(key + i + 4);
        u16x8 r;
        r[0] = f2bf(a[0]); r[1] = f2bf(a[1]); r[2] = f2bf(a[2]); r[3] = f2bf(a[3]);
        r[4] = f2bf(c[0]); r[5] = f2bf(c[1]); r[6] = f2bf(c[2]); r[7] = f2bf(c[3]);
        *(u16x8*)(keyb + i) = r;
        return;
    }
    int b2 = b - 32768;
    if (b2 < 2048) {
        const float* s = Wt + (size_t)b2 * 5121;
        unsigned short* d = Wtk + (size_t)b2 * 2048;
#pragma unroll
        for (int k = 0; k < 8; k++) { int c = tid + (k << 8); d[c] = f2bf(s[c]); }
    } else if (b2 < 4096) {
        int o = b2 - 2048;
        const float* s = Wq + (size_t)o * 3073;
        unsigned short* d = Wqk + (size_t)o * 2048;
#pragma unroll
        for (int k = 0; k < 8; k++) { int c = tid + (k << 8); d[c] = f2bf(s[c]); }
    } else if (b2 < 5120) {
        long i = ((long)(b2 - 4096) * 256 + tid) * 8;
        f4v a = *(const f4v*)(q_key + i);
        f4v c = *(const f4v*)(q_key + i + 4);
        u16x8 r;
        r[0] = f2bf(a[0]); r[1] = f2bf(a[1]); r[2] = f2bf(a[2]); r[3] = f2bf(a[3]);
        r[4] = f2bf(c[0]); r[5] = f2bf(c[1]); r[6] = f2bf(c[2]); r[7] = f2bf(c[3]);
        *(u16x8*)(qkb + i) = r;
    } else {
        int o = (b2 - 5120) * 256 + tid;
        w3q[o] = Wq[(size_t)o * 3073 + 3072];
        w3t[o] = Wt[(size_t)o * 5121 + 3072];
    }
}

// ---------- per-batch constant D[b][o] ----------
template <int KLEN>
__global__ __launch_bounds__(256) void dconst_kernel(
    const float* __restrict__ W, long ldw,
    const float* __restrict__ bias,
    const float* __restrict__ query,
    const float* __restrict__ qctx,
    float* __restrict__ Dout) {
    int tid = threadIdx.x;
    int wave = tid >> 6, lane = tid & 63;
    int o = blockIdx.x * 4 + wave;
    const float* wrow = W + (size_t)o * ldw + 2048;
    float acc[16];
#pragma unroll
    for (int b2 = 0; b2 < 16; b2++) acc[b2] = 0.f;
    for (int i = lane; i < KLEN; i += 64) {
        if (KLEN == 1024 || i < 1024) {
            float wv = wrow[i];
            const float* qp = query + i;
#pragma unroll
            for (int b2 = 0; b2 < 16; b2++) acc[b2] += wv * qp[b2 * 1024];
        } else {
            float wv = wrow[i + 1];  // skip alphas column at 3072
            const float* cp = qctx + (i - 1024);
#pragma unroll
            for (int b2 = 0; b2 < 16; b2++) acc[b2] += wv * cp[b2 * 2048];
        }
    }
#pragma unroll
    for (int b2 = 0; b2 < 16; b2++) {
        float v = acc[b2];
        for (int off = 1; off < 64; off <<= 1) v += __shfl_xor(v, off);
        if (lane == 0) Dout[(b2 << 11) + o] = v + bias[o];
    }
}

// ---------- query-side fused GEMM (128x128 tile, m97 structure) ----------
template <int LOG_RPB>
__global__ __launch_bounds__(256) void gemm_score(
    const unsigned short* __restrict__ A,
    const unsigned short* __restrict__ Bt,
    const float* __restrict__ Dc,
    const float* __restrict__ avec,
    const float* __restrict__ w3,
    const float* __restrict__ tvec,
    float* __restrict__ partial,
    int row0) {
    __shared__ unsigned short As[128 * 32];
    __shared__ unsigned short Bs[128 * 32];
    __shared__ float red[128][2];

    int nwg = gridDim.x;
    int bid = blockIdx.x;
    int q8 = nwg >> 3;
    int wg = (bid & 7) * q8 + (bid >> 3);
    int rb = wg >> 4, cb = wg & 15;

    int tid = threadIdx.x;
    int wave = tid >> 6, lane = tid & 63;
    int wr = wave >> 1, wc = wave & 1;
    int l15 = lane & 15, lhi = lane >> 4;

    const unsigned short* Ab = A + (size_t)rb * 128 * GK;
    const unsigned short* Bb = Bt + (size_t)cb * 128 * GK;

    int r0 = tid >> 2, c0 = (tid & 3) << 3;

    f32x4 acc[4][4];
#pragma unroll
    for (int i = 0; i < 4; i++)
#pragma unroll
        for (int j = 0; j < 4; j++) acc[i][j] = (f32x4)0.f;

    unsigned short* AsW0 = As + (wave << 9);
    unsigned short* AsW1 = As + 2048 + (wave << 9);
    unsigned short* BsW0 = Bs + (wave << 9);
    unsigned short* BsW1 = Bs + 2048 + (wave << 9);

    for (int k0 = 0; k0 < GK; k0 += 32) {
        __syncthreads();
        gl_lds16(Ab + (size_t)r0 * GK + k0 + c0, AsW0);
        gl_lds16(Ab + (size_t)(r0 + 64) * GK + k0 + c0, AsW1);
        gl_lds16(Bb + (size_t)r0 * GK + k0 + c0, BsW0);
        gl_lds16(Bb + (size_t)(r0 + 64) * GK + k0 + c0, BsW1);
        __syncthreads();
        bf16x8 a[4], b[4];
#pragma unroll
        for (int mi = 0; mi < 4; mi++)
            a[mi] = *(const bf16x8*)(As + (((wr << 6) + (mi << 4) + l15) << 5) + (lhi << 3));
#pragma unroll
        for (int ni = 0; ni < 4; ni++)
            b[ni] = *(const bf16x8*)(Bs + (((wc << 6) + (ni << 4) + l15) << 5) + (lhi << 3));
#pragma unroll
        for (int mi = 0; mi < 4; mi++)
#pragma unroll
            for (int ni = 0; ni < 4; ni++)
                acc[mi][ni] = __builtin_amdgcn_mfma_f32_16x16x32_bf16(a[mi], b[ni], acc[mi][ni], 0, 0, 0);
    }

    int grow_base = row0 + (rb << 7) + (wr << 6);
    int bb = grow_base >> LOG_RPB;
    int gcol = (cb << 7) + (wc << 6) + l15;
    float Dco[4], w3o[4], tv[4];
#pragma unroll
    for (int ni = 0; ni < 4; ni++) {
        int o = gcol + (ni << 4);
        Dco[ni] = Dc[(bb << 11) + o];
        w3o[ni] = w3[o];
        tv[ni] = tvec[o];
    }
#pragma unroll
    for (int mi = 0; mi < 4; mi++) {
#pragma unroll
        for (int j = 0; j < 4; j++) {
            int rloc = (mi << 4) + (lhi << 2) + j;
            float av = avec[grow_base + rloc];
            float s = 0.f;
#pragma unroll
            for (int ni = 0; ni < 4; ni++) {
                float x = acc[mi][ni][j] + Dco[ni] + av * w3o[ni];
                x = fminf(fmaxf(x, -15.f), 15.f);
                float e = __expf(2.f * x);
                s += ((e - 1.f) / (e + 1.f)) * tv[ni];
            }
#pragma unroll
            for (int off = 1; off < 16; off <<= 1) s += __shfl_xor(s, off);
            if (l15 == 0) red[(wr << 6) + rloc][wc] = s;
        }
    }
    __syncthreads();
    if (tid < 128) {
        partial[(size_t)(row0 + (rb << 7) + tid) * NCB + cb] = red[tid][0] + red[tid][1];
    }
}

// ---------- text-side 256x256 8-phase GEMM (r2 structure, hoisted LDS addrs) ----------
// LDS layout (ushort units): XA=0, YA=16384, XB=32768, YB=49152, red @65536.
// Y-group = X-group + 32768 BYTES. Read addrs fully hoisted: aA0/aA1[8] (mi=0..7),
// bB0/bB1[4] (ni=0..3). Swizzle: chunk p of row r holds global chunk p^(r&7).
#define MFMA16(A, B, C) __builtin_amdgcn_mfma_f32_16x16x32_bf16(A, B, C, 0, 0, 0)

#define STAGE2(GB, GR0, K0, LB) do { \
    int _rr = lane >> 3; \
    int _cc = ((lane & 7) ^ _rr) << 3; \
    gl_lds16((GB) + (size_t)((GR0) + (wid << 3) + _rr) * GK + (K0) + _cc, lds + (LB) + (wid << 9)); \
    gl_lds16((GB) + (size_t)((GR0) + 64 + (wid << 3) + _rr) * GK + (K0) + _cc, lds + (LB) + 4096 + (wid << 9)); \
  } while (0)

#define WAIT4 do { asm volatile("s_waitcnt vmcnt(4)" ::: "memory"); __builtin_amdgcn_sched_barrier(0); } while (0)
#define NOWAIT do { } while (0)

#define PHASE(YOFF, Q, FIRSTB, STAGE_STMT, BOUNDARY) do { \
    bf16x8 a00, a01, a10, a11; \
    if (FIRSTB) { \
        b00 = *(const bf16x8*)(lds8 + bB0[0] + (YOFF)); b01 = *(const bf16x8*)(lds8 + bB1[0] + (YOFF)); \
        b10 = *(const bf16x8*)(lds8 + bB0[1] + (YOFF)); b11 = *(const bf16x8*)(lds8 + bB1[1] + (YOFF)); \
        b20 = *(const bf16x8*)(lds8 + bB0[2] + (YOFF)); b21 = *(const bf16x8*)(lds8 + bB1[2] + (YOFF)); \
        b30 = *(const bf16x8*)(lds8 + bB0[3] + (YOFF)); b31 = *(const bf16x8*)(lds8 + bB1[3] + (YOFF)); \
    } \
    a00 = *(const bf16x8*)(lds8 + aA0[2*(Q)  ] + (YOFF)); a01 = *(const bf16x8*)(lds8 + aA1[2*(Q)  ] + (YOFF)); \
    a10 = *(const bf16x8*)(lds8 + aA0[2*(Q)+1] + (YOFF)); a11 = *(const bf16x8*)(lds8 + aA1[2*(Q)+1] + (YOFF)); \
    STAGE_STMT; \
    BOUNDARY; \
    __builtin_amdgcn_s_barrier(); \
    asm volatile("s_waitcnt lgkmcnt(0)" ::: "memory"); \
    __builtin_amdgcn_sched_barrier(0); \
    __builtin_amdgcn_s_setprio(1); \
    acc[2*(Q)  ][0] = MFMA16(a00, b00, acc[2*(Q)  ][0]); \
    acc[2*(Q)  ][0] = MFMA16(a01, b01, acc[2*(Q)  ][0]); \
    acc[2*(Q)  ][1] = MFMA16(a00, b10, acc[2*(Q)  ][1]); \
    acc[2*(Q)  ][1] = MFMA16(a01, b11, acc[2*(Q)  ][1]); \
    acc[2*(Q)  ][2] = MFMA16(a00, b20, acc[2*(Q)  ][2]); \
    acc[2*(Q)  ][2] = MFMA16(a01, b21, acc[2*(Q)  ][2]); \
    acc[2*(Q)  ][3] = MFMA16(a00, b30, acc[2*(Q)  ][3]); \
    acc[2*(Q)  ][3] = MFMA16(a01, b31, acc[2*(Q)  ][3]); \
    acc[2*(Q)+1][0] = MFMA16(a10, b00, acc[2*(Q)+1][0]); \
    acc[2*(Q)+1][0] = MFMA16(a11, b01, acc[2*(Q)+1][0]); \
    acc[2*(Q)+1][1] = MFMA16(a10, b10, acc[2*(Q)+1][1]); \
    acc[2*(Q)+1][1] = MFMA16(a11, b11, acc[2*(Q)+1][1]); \
    acc[2*(Q)+1][2] = MFMA16(a10, b20, acc[2*(Q)+1][2]); \
    acc[2*(Q)+1][2] = MFMA16(a11, b21, acc[2*(Q)+1][2]); \
    acc[2*(Q)+1][3] = MFMA16(a10, b30, acc[2*(Q)+1][3]); \
    acc[2*(Q)+1][3] = MFMA16(a11, b31, acc[2*(Q)+1][3]); \
    __builtin_amdgcn_s_setprio(0); \
    __builtin_amdgcn_sched_barrier(0); \
    __builtin_amdgcn_s_barrier(); \
  } while (0)

__global__ __launch_bounds__(512, 2) void gemm256(
    const unsigned short* __restrict__ A,
    const unsigned short* __restrict__ Bt,
    const float* __restrict__ Dc,
    const float* __restrict__ avec,
    const float* __restrict__ w3,
    const float* __restrict__ tvec,
    float* __restrict__ partial) {
    extern __shared__ unsigned short lds[];
    char* lds8 = (char*)lds;
    const int XA = 0, YA = 16384, XB = 32768, YB = 49152;  // ushort units

    int nwg = gridDim.x;
    int bid = blockIdx.x;
    int q8 = nwg >> 3;
    int wg = (bid & 7) * q8 + (bid >> 3);   // bijective XCD swizzle (nwg % 8 == 0)
    int rb = wg >> 3, cb = wg & 7;

    int tid = threadIdx.x;
    int wid = tid >> 6, lane = tid & 63;
    int wr = wid >> 2, wc = wid & 3;
    int l15 = lane & 15, lhi = lane >> 4;

    const unsigned short* Aq = A;
    const unsigned short* Bq = Bt;
    int arow = rb << 8;
    int brow = cb << 8;

    // hoisted LDS read addresses (bytes, X-group base; Y-group = +32768)
    int sw0 = ((lhi ^ (l15 & 7)) << 4);
    int sw1 = (((4 | lhi) ^ (l15 & 7)) << 4);
    int aA0[8], aA1[8], bB0[4], bB1[4];
#pragma unroll
    for (int mi = 0; mi < 8; mi++) {           // wave's 128 A-rows: wr*128 + mi*16 + l15
        int r = (wr << 7) + (mi << 4) + l15;
        aA0[mi] = (r << 7) + sw0;
        aA1[mi] = (r << 7) + sw1;
    }
#pragma unroll
    for (int ni = 0; ni < 4; ni++) {           // wave's 64 B-cols: wc*64 + ni*16 + l15
        int r = (wc << 6) + (ni << 4) + l15;
        bB0[ni] = 65536 + (r << 7) + sw0;
        bB1[ni] = 65536 + (r << 7) + sw1;
    }

    f32x4 acc[8][4];
#pragma unroll
    for (int i = 0; i < 8; i++)
#pragma unroll
        for (int j = 0; j < 4; j++) acc[i][j] = (f32x4)0.f;

    bf16x8 b00, b01, b10, b11, b20, b21, b30, b31;

    // prologue: X <- tile0 (B then A), Y.B <- tile1
    STAGE2(Bq, brow, 0, XB);
    STAGE2(Bq, brow + 128, 0, XB + 8192);
    STAGE2(Aq, arow, 0, XA);
    STAGE2(Aq, arow + 128, 0, XA + 8192);
    STAGE2(Bq, brow, 64, YB);
    STAGE2(Bq, brow + 128, 64, YB + 8192);
    asm volatile("s_waitcnt vmcnt(4)" ::: "memory");
    __builtin_amdgcn_sched_barrier(0);
    __builtin_amdgcn_s_barrier();

    for (int it = 0; it < 16; ++it) {
        int k1 = ((it << 1) + 1) << 6;           // tile 2i+1 A (real)
        int k2 = (((it << 1) + 2) << 6) & 2047;  // tile 2i+2 (masked harmless on last iter)
        int k3 = (((it << 1) + 3) << 6) & 2047;  // tile 2i+3
        PHASE(0,     0, 1, STAGE2(Aq, arow,       k1, YA),        NOWAIT);
        PHASE(0,     1, 0, STAGE2(Aq, arow + 128, k1, YA + 8192), NOWAIT);
        PHASE(0,     2, 0, STAGE2(Bq, brow,       k2, XB),        NOWAIT);
        PHASE(0,     3, 0, STAGE2(Bq, brow + 128, k2, XB + 8192), WAIT4);
        PHASE(32768, 0, 1, STAGE2(Aq, arow,       k2, XA),        NOWAIT);
        PHASE(32768, 1, 0, STAGE2(Aq, arow + 128, k2, XA + 8192), NOWAIT);
        PHASE(32768, 2, 0, STAGE2(Bq, brow,       k3, YB),        NOWAIT);
        PHASE(32768, 3, 0, STAGE2(Bq, brow + 128, k3, YB + 8192), WAIT4);
    }

    // epilogue: fused tanh-dot partial scores
    int gcolb = (cb << 8) + (wc << 6) + l15;
    int bb = rb >> 3;   // 2048 rows per batch, 256 rows per rb
    float Dco[4], w3o[4], tv[4];
#pragma unroll
    for (int ni = 0; ni < 4; ++ni) {
        int o = gcolb + (ni << 4);
        Dco[ni] = Dc[(bb << 11) + o];
        w3o[ni] = w3[o];
        tv[ni] = tvec[o];
    }
    float* red = (float*)(lds + 65536);  // [256][4]
#pragma unroll
    for (int mi = 0; mi < 8; ++mi) {
#pragma unroll
        for (int j = 0; j < 4; ++j) {
            int rloc = (wr << 7) + (mi << 4) + (lhi << 2) + j;
            float av = avec[(rb << 8) + rloc];
            float s = 0.f;
#pragma unroll
            for (int ni = 0; ni < 4; ++ni) {
                float x = acc[mi][ni][j] + Dco[ni] + av * w3o[ni];
                x = fminf(fmaxf(x, -15.f), 15.f);
                float e = __expf(2.f * x);
                s += ((e - 1.f) / (e + 1.f)) * tv[ni];
            }
#pragma unroll
            for (int off2 = 1; off2 < 16; off2 <<= 1) s += __shfl_xor(s, off2);
            if (l15 == 0) red[(rloc << 2) + wc] = s;
        }
    }
    __syncthreads();
    if (tid < 256) {
        partial[(size_t)((rb << 8) + tid) * 8 + cb] =
            red[(tid << 2)] + red[(tid << 2) + 1] + red[(tid << 2) + 2] + red[(tid << 2) + 3];
    }
}

// ---------- query softmax (alphas only) ----------
__global__ void softmax_q_alphas(const float* __restrict__ partial_q,
                                 const int* __restrict__ q_mask,
                                 float* __restrict__ out_qalphas) {
    int b = blockIdx.x, tid = threadIdx.x;  // 64 threads
    float s = 0.f;
    const float* p = partial_q + (size_t)(b * 64 + tid) * NCB;
#pragma unroll
    for (int c = 0; c < 16; c++) s += p[c];
    if (q_mask[b * 64 + tid] == 0) s = -INFINITY;
    float m = s;
    for (int off = 1; off < 64; off <<= 1) m = fmaxf(m, __shfl_xor(m, off));
    float e = (s == -INFINITY) ? 0.f : __expf(s - m);
    float sum = e;
    for (int off = 1; off < 64; off <<= 1) sum += __shfl_xor(sum, off);
    out_qalphas[b * 64 + tid] = e / sum;
}

// ---------- q_context = q_alphas @ q_value ----------
__global__ __launch_bounds__(256) void qctx_kernel(
    const float* __restrict__ qal, const float* __restrict__ q_value,
    float* __restrict__ qctx) {
    int b = blockIdx.x, dc = blockIdx.y, tid = threadIdx.x;
    __shared__ float sal[64];
    if (tid < 64) sal[tid] = qal[b * 64 + tid];
    __syncthreads();
    int d = (dc << 8) + tid;
    float acc = 0.f;
    for (int l = 0; l < 64; l++) {
        float al = sal[l];
        if (al != 0.f) acc += al * q_value[((size_t)(b * 64 + l) << 11) + d];
    }
    qctx[(b << 11) + d] = acc;
}

// ---------- text softmax (stride-8 partials) ----------
__global__ __launch_bounds__(256) void softmax_t_kernel(
    const float* __restrict__ partial,
    const int* __restrict__ mask,
    float* __restrict__ out_alphas) {
    int b = blockIdx.x, tid = threadIdx.x;
    int wave = tid >> 6, lane = tid & 63;
    __shared__ float sred[4];
    float sc[8];
    float lm = -INFINITY;
#pragma unroll
    for (int i = 0; i < 8; i++) {
        int l = tid + (i << 8);
        const float* p = partial + (size_t)(b * 2048 + l) * 8;
        float s = 0.f;
#pragma unroll
        for (int c = 0; c < 8; c++) s += p[c];
        if (mask[b * 2048 + l] == 0) s = -INFINITY;
        sc[i] = s;
        lm = fmaxf(lm, s);
    }
    for (int off = 1; off < 64; off <<= 1) lm = fmaxf(lm, __shfl_xor(lm, off));
    if (lane == 0) sred[wave] = lm;
    __syncthreads();
    float m = fmaxf(fmaxf(sred[0], sred[1]), fmaxf(sred[2], sred[3]));
    float ee[8];
    float ls = 0.f;
#pragma unroll
    for (int i = 0; i < 8; i++) {
        ee[i] = (sc[i] == -INFINITY) ? 0.f : __expf(sc[i] - m);
        ls += ee[i];
    }
    for (int off = 1; off < 64; off <<= 1) ls += __shfl_xor(ls, off);
    __syncthreads();
    if (lane == 0) sred[wave] = ls;
    __syncthreads();
    float S = sred[0] + sred[1] + sred[2] + sred[3];
    float inv = 1.f / S;
#pragma unroll
    for (int i = 0; i < 8; i++)
        out_alphas[b * 2048 + tid + (i << 8)] = ee[i] * inv;
}

// ---------- context = alphas @ value ----------
__global__ __launch_bounds__(256) void ctx_partial_kernel(
    const float* __restrict__ alphas,
    const float* __restrict__ value,
    float* __restrict__ pctx) {
    int b = blockIdx.x, lc = blockIdx.y, tid = threadIdx.x;
    __shared__ float sa[128];
    if (tid < 128) sa[tid] = alphas[(b << 11) + (lc << 7) + tid];
    __syncthreads();
    f4v a0 = (f4v)0.f, a1 = (f4v)0.f;
    const float* vb = value + ((size_t)((b << 11) + (lc << 7)) << 11);
    for (int l = 0; l < 128; l++) {
        float al = sa[l];
        if (al != 0.f) {  // block-uniform branch; masked rows skipped
            const f4v* vr = (const f4v*)(vb + ((size_t)l << 11));
            a0 += al * vr[tid];
            a1 += al * vr[tid + 256];
        }
    }
    f4v* p = (f4v*)(pctx + ((size_t)((b << 4) + lc) << 11));
    p[tid] = a0;
    p[tid + 256] = a1;
}

__global__ __launch_bounds__(256) void ctx_reduce_kernel(
    const float* __restrict__ pctx, float* __restrict__ out_ctx) {
    int b = blockIdx.x, half = blockIdx.y, tid = threadIdx.x;
    int d4 = (half << 8) + tid;
    f4v s = (f4v)0.f;
#pragma unroll
    for (int lc = 0; lc < 16; lc++)
        s += ((const f4v*)(pctx + ((size_t)((b << 4) + lc) << 11)))[d4];
    ((f4v*)(out_ctx + ((size_t)b << 11)))[d4] = s;
}

// ---------- losses ----------
__global__ void loss_part_kernel(const float* __restrict__ qs, const float* __restrict__ qa,
                                 const float* __restrict__ ts, const float* __restrict__ ta,
                                 float* __restrict__ parts) {
    int blk = blockIdx.x, tid = threadIdx.x;  // 128 threads
    int wave = tid >> 6, lane = tid & 63;
    __shared__ float sred[2];
    float s = 0.f;
    if (blk == 0) {
        if (tid < 64) {
            float m = INFINITY;
#pragma unroll
            for (int b = 0; b < 16; ++b) {
                m = fminf(m, qs[(b << 6) + tid]);
                m = fminf(m, qa[(b << 6) + tid]);
            }
            s = m;
        }
    } else {
        int l = ((blk - 1) << 7) + tid;
        float m = INFINITY;
#pragma unroll
        for (int b = 0; b < 16; ++b) {
            m = fminf(m, ts[(b << 11) + l]);
            m = fminf(m, ta[(b << 11) + l]);
        }
        s = m;
    }
    for (int off = 1; off < 64; off <<= 1) s += __shfl_xor(s, off);
    if (lane == 0) sred[wave] = s;
    __syncthreads();
    if (tid == 0) parts[blk] = sred[0] + sred[1];
}

__global__ void loss_final_kernel(const float* __restrict__ parts,
                                  float* __restrict__ out_tl, float* __restrict__ out_ql) {
    if (threadIdx.x == 0) {
        *out_ql = parts[0];
        float t = 0.f;
        for (int i = 1; i <= 16; ++i) t += parts[i];
        *out_tl = t;
    }
}

extern "C" void kernel_launch(void* const* d_in, const int* in_sizes, int n_in,
                              void* d_out, int out_size, void* d_ws, size_t ws_size,
                              hipStream_t stream) {
    const float* query          = (const float*)d_in[0];
    const float* key            = (const float*)d_in[1];
    const float* value          = (const float*)d_in[2];
    const int*   mask           = (const int*)d_in[3];
    const float* q_key          = (const float*)d_in[4];
    const float* q_value        = (const float*)d_in[5];
    const int*   q_mask         = (const int*)d_in[6];
    const float* alphas_state   = (const float*)d_in[7];
    const float* q_alphas_state = (const float*)d_in[8];
    const float* W_q            = (const float*)d_in[9];
    const float* b_q            = (const float*)d_in[10];
    const float* W_t            = (const float*)d_in[11];
    const float* b_t            = (const float*)d_in[12];
    const float* query_other    = (const float*)d_in[13];
    const float* text_other     = (const float*)d_in[14];

    float* out        = (float*)d_out;
    float* out_ctx     = out;            // 16*2048
    float* out_alphas  = out + 32768;    // 16*2048
    float* out_qalphas = out + 65536;    // 16*64
    float* out_tloss   = out + 66560;
    float* out_qloss   = out + 66561;

    char* w = (char*)d_ws;
    size_t off = 0;
    auto alloc = [&](size_t bytes) -> char* {
        char* p = w + off;
        off += (bytes + 255) & ~(size_t)255;
        return p;
    };
    unsigned short* Wtk  = (unsigned short*)alloc(2048ull * 2048 * 2);
    unsigned short* Wqk  = (unsigned short*)alloc(2048ull * 2048 * 2);
    unsigned short* qkb  = (unsigned short*)alloc(1024ull * 2048 * 2);
    unsigned short* keyb = (unsigned short*)alloc(32768ull * 2048 * 2);
    float* partial_t     = (float*)alloc(32768ull * 8 * 4);
    float* partial_q     = (float*)alloc(1024ull * NCB * 4);
    float* Dq            = (float*)alloc(16 * 2048 * 4);
    float* Dt            = (float*)alloc(16 * 2048 * 4);
    float* qctx          = (float*)alloc(16 * 2048 * 4);
    float* w3q           = (float*)alloc(2048 * 4);
    float* w3t           = (float*)alloc(2048 * 4);
    float* pctx          = (float*)alloc(16ull * 16 * 2048 * 4);
    float* lparts        = (float*)alloc(32 * 4);

    hipFuncSetAttribute((const void*)gemm256,
                        hipFuncAttributeMaxDynamicSharedMemorySize, 135168);

    // merged conversions (key + weights + q_key + w3)
    prep_kernel<<<37896, 256, 0, stream>>>(W_t, W_q, q_key, key,
                                           Wtk, Wqk, qkb, keyb, w3q, w3t);
    dconst_kernel<1024><<<512, 256, 0, stream>>>(W_q, 3073, b_q, query, nullptr, Dq);

    // query-side GEMM + softmax + context
    gemm_score<6><<<128, 256, 0, stream>>>(qkb, Wqk, Dq, q_alphas_state, w3q,
                                           query_other, partial_q, 0);
    softmax_q_alphas<<<16, 64, 0, stream>>>(partial_q, q_mask, out_qalphas);
    qctx_kernel<<<dim3(16, 8), 256, 0, stream>>>(out_qalphas, q_value, qctx);

    // text-side constants, then bf16 GEMM over all 32768 rows
    dconst_kernel<3072><<<512, 256, 0, stream>>>(W_t, 5121, b_t, query, qctx, Dt);
    gemm256<<<1024, 512, 135168, stream>>>(keyb, Wtk, Dt, alphas_state, w3t,
                                           text_other, partial_t);

    softmax_t_kernel<<<16, 256, 0, stream>>>(partial_t, mask, out_alphas);
    ctx_partial_kernel<<<dim3(16, 16), 256, 0, stream>>>(out_alphas, value, pctx);
    ctx_reduce_kernel<<<dim3(16, 2), 256, 0, stream>>>(pctx, out_ctx);
    loss_part_kernel<<<17, 128, 0, stream>>>(q_alphas_state, out_qalphas,
                                             alphas_state, out_alphas, lparts);
    loss_final_kernel<<<1, 64, 0, stream>>>(lparts, out_tloss, out_qloss);
}